// Round 6
// baseline (510.260 us; speedup 1.0000x reference)
//
#include <hip/hip_runtime.h>

#define CH 64
#define NBUCK 1024        // buckets = dst >> 7 (128 nodes/bucket); needs N <= 131072
#define BSHIFT 7
#define BMASK 127
#define NBLK_P 128        // partition blocks; must match k_hist/k_partition/k_bucketscan

// ---- CSR build: scatter-free two-level bucket sort ------------------------

__global__ __launch_bounds__(256) void k_hist(const int* __restrict__ dst,
                                              int* __restrict__ blkhist, int E) {
    __shared__ int h[NBUCK];
    for (int i = threadIdx.x; i < NBUCK; i += blockDim.x) h[i] = 0;
    __syncthreads();
    int chunk = (E + NBLK_P - 1) / NBLK_P;
    int beg = blockIdx.x * chunk;
    int end = min(beg + chunk, E);
    for (int e = beg + threadIdx.x; e < end; e += blockDim.x)
        atomicAdd(&h[dst[e] >> BSHIFT], 1);
    __syncthreads();
    for (int i = threadIdx.x; i < NBUCK; i += blockDim.x)
        blkhist[blockIdx.x * NBUCK + i] = h[i];
}

// One wave per bucket: scan blkhist[b][t] along b (128 values, 2/lane).
// off_t[t*128+b] = exclusive within-bucket prefix; tot[t] = bucket total.
__global__ __launch_bounds__(256) void k_bucketscan(const int* __restrict__ blkhist,
                                                    int* __restrict__ off_t,
                                                    int* __restrict__ tot) {
    int lane = threadIdx.x & 63;
    int t = (blockIdx.x * blockDim.x + threadIdx.x) >> 6;   // bucket id 0..1023
    int b0 = lane * 2, b1 = b0 + 1;
    int v0 = blkhist[b0 * NBUCK + t];
    int v1 = blkhist[b1 * NBUCK + t];
    int ps = v0 + v1;
    int sc = ps;
#pragma unroll
    for (int o = 1; o < 64; o <<= 1) {
        int u = __shfl_up(sc, o, 64);
        if (lane >= o) sc += u;
    }
    int excl = sc - ps;
    off_t[t * NBLK_P + b0] = excl;
    off_t[t * NBLK_P + b1] = excl + v0;
    if (lane == 63) tot[t] = sc;
}

// Single small block: exclusive scan of 1024 bucket totals -> bbase.
__global__ __launch_bounds__(1024) void k_scantot(const int* __restrict__ tot,
                                                  int* __restrict__ bbase,
                                                  int* __restrict__ row_ptr, int n) {
    __shared__ int sh[NBUCK];
    int t = threadIdx.x;
    int v = tot[t];
    sh[t] = v;
    __syncthreads();
    for (int o = 1; o < NBUCK; o <<= 1) {
        int u = (t >= o) ? sh[t - o] : 0;
        __syncthreads();
        sh[t] += u;
        __syncthreads();
    }
    bbase[t] = sh[t] - v;
    if (t == NBUCK - 1) {
        bbase[NBUCK] = sh[t];
        row_ptr[n]   = sh[t];
    }
}

__global__ __launch_bounds__(256) void k_partition(const int* __restrict__ src,
                                                   const int* __restrict__ dst,
                                                   const int* __restrict__ off_t,
                                                   const int* __restrict__ bbase,
                                                   unsigned int* __restrict__ ebuf, int E) {
    __shared__ int cur[NBUCK];
    for (int i = threadIdx.x; i < NBUCK; i += blockDim.x)
        cur[i] = bbase[i] + off_t[i * NBLK_P + blockIdx.x];
    __syncthreads();
    int chunk = (E + NBLK_P - 1) / NBLK_P;
    int beg = blockIdx.x * chunk;
    int end = min(beg + chunk, E);
    for (int e = beg + threadIdx.x; e < end; e += blockDim.x) {
        int s = src[e];
        int d = dst[e];
        int p = atomicAdd(&cur[d >> BSHIFT], 1);
        ebuf[p] = ((unsigned int)(d & BMASK) << 17) | (unsigned int)s;
    }
}

__global__ __launch_bounds__(128) void k_bucket_csr(const unsigned int* __restrict__ ebuf,
                                                    const int* __restrict__ bbase,
                                                    int* __restrict__ row_ptr,
                                                    float* __restrict__ dinv,
                                                    int* __restrict__ col, int n) {
    __shared__ int cnt[128];
    __shared__ int cur[128];
    __shared__ int sc[128];
    int t = threadIdx.x;
    int k = blockIdx.x;
    int e0 = bbase[k], e1 = bbase[k + 1];
    cnt[t] = 0;
    __syncthreads();
    for (int e = e0 + t; e < e1; e += 128)
        atomicAdd(&cnt[ebuf[e] >> 17], 1);
    __syncthreads();
    int c = cnt[t];
    sc[t] = c;
    __syncthreads();
    for (int o = 1; o < 128; o <<= 1) {
        int v = (t >= o) ? sc[t - o] : 0;
        __syncthreads();
        sc[t] += v;
        __syncthreads();
    }
    int excl = sc[t] - c;
    int node = (k << BSHIFT) + t;
    if (node < n) {
        row_ptr[node] = e0 + excl;
        dinv[node] = rsqrtf((float)(c + 1));   // +1 self-loop
    }
    cur[t] = e0 + excl;
    __syncthreads();
    for (int e = e0 + t; e < e1; e += 128) {
        unsigned int u = ebuf[e];
        int p = atomicAdd(&cur[u >> 17], 1);
        col[p] = (int)(u & 0x1FFFFu);
    }
}

// ---- GEMM: wave-per-node, W in LDS, x-row broadcast via shuffle -----------

__global__ __launch_bounds__(256) void k_gemm64(const float* __restrict__ in,
                                                const float* __restrict__ W,
                                                const float* __restrict__ dinv,
                                                float* __restrict__ hs, int n) {
    __shared__ float Ws[CH * CH];
    for (int i = threadIdx.x; i < CH * CH; i += blockDim.x) Ws[i] = W[i];
    __syncthreads();

    int lane = threadIdx.x & 63;
    int wid  = (blockIdx.x * blockDim.x + threadIdx.x) >> 6;
    int nw   = (gridDim.x * blockDim.x) >> 6;

    for (int node = wid; node < n; node += nw) {
        float v = in[(size_t)node * CH + lane];
        float acc = 0.0f;
#pragma unroll
        for (int k = 0; k < CH; ++k)
            acc = fmaf(__shfl(v, k, 64), Ws[k * CH + lane], acc);
        hs[(size_t)node * CH + lane] = acc * dinv[node];
    }
}

// ---- fused gather + relu/bias + GEMM(W2) + dot(Wl) -> z -------------------
// Quad-node float4 layout: 4 nodes/wave, 16 lanes/node, lane holds 4 channels.
// Each neighbor-row load is dwordx4; one instruction fetches 4 rows (1 KB).

__global__ __launch_bounds__(256) void k_gather_gemm(const int* __restrict__ row_ptr,
                                                     const int* __restrict__ col,
                                                     const float* __restrict__ hs,
                                                     const float* __restrict__ dinv,
                                                     const float* __restrict__ W,
                                                     const float* __restrict__ bias,
                                                     const float* __restrict__ Wl,
                                                     float* __restrict__ z, int n) {
    __shared__ float Ws[CH * CH];   // [k][c] row-major, same as W
    for (int i = threadIdx.x; i < CH * CH; i += blockDim.x) Ws[i] = W[i];
    __syncthreads();

    const float4* hs4 = (const float4*)hs;

    int lane  = threadIdx.x & 63;
    int g     = lane >> 4;          // node group 0..3
    int l     = lane & 15;          // lane within group: channels 4l..4l+3
    int gbase = lane & 48;          // g*16
    int wid   = (blockIdx.x * blockDim.x + threadIdx.x) >> 6;
    int nw    = (gridDim.x * blockDim.x) >> 6;

    float4 bi  = *(const float4*)(bias + 4 * l);
    float4 wl4 = *(const float4*)(Wl + 4 * l);

    for (int node0 = wid * 4; node0 < n; node0 += nw * 4) {
        int node = node0 + g;
        int nc   = min(node, n - 1);
        float4 acc = hs4[(size_t)nc * 16 + l];          // self-loop row
        int beg = row_ptr[nc];
        int deg = row_ptr[nc + 1] - beg;
        if (node >= n) deg = 0;

        for (int e = 0; __any(e < deg); e += 16) {
            int idx = (e + l < deg) ? col[beg + e + l] : 0;  // 16 idx per group
            int lim = deg - e;                               // group-uniform
            if (lim >= 16) {
#pragma unroll
                for (int j0 = 0; j0 < 16; j0 += 8) {
                    int s0 = __shfl(idx, gbase + j0 + 0, 64);
                    int s1 = __shfl(idx, gbase + j0 + 1, 64);
                    int s2 = __shfl(idx, gbase + j0 + 2, 64);
                    int s3 = __shfl(idx, gbase + j0 + 3, 64);
                    int s4 = __shfl(idx, gbase + j0 + 4, 64);
                    int s5 = __shfl(idx, gbase + j0 + 5, 64);
                    int s6 = __shfl(idx, gbase + j0 + 6, 64);
                    int s7 = __shfl(idx, gbase + j0 + 7, 64);
                    float4 a0 = hs4[(size_t)s0 * 16 + l];
                    float4 a1 = hs4[(size_t)s1 * 16 + l];
                    float4 a2 = hs4[(size_t)s2 * 16 + l];
                    float4 a3 = hs4[(size_t)s3 * 16 + l];
                    float4 a4 = hs4[(size_t)s4 * 16 + l];
                    float4 a5 = hs4[(size_t)s5 * 16 + l];
                    float4 a6 = hs4[(size_t)s6 * 16 + l];
                    float4 a7 = hs4[(size_t)s7 * 16 + l];
                    acc.x += a0.x + a1.x + a2.x + a3.x + a4.x + a5.x + a6.x + a7.x;
                    acc.y += a0.y + a1.y + a2.y + a3.y + a4.y + a5.y + a6.y + a7.y;
                    acc.z += a0.z + a1.z + a2.z + a3.z + a4.z + a5.z + a6.z + a7.z;
                    acc.w += a0.w + a1.w + a2.w + a3.w + a4.w + a5.w + a6.w + a7.w;
                }
            } else {
                for (int j = 0; j < lim; ++j) {              // lim group-uniform
                    int s = __shfl(idx, gbase + j, 64);
                    float4 a = hs4[(size_t)s * 16 + l];
                    acc.x += a.x; acc.y += a.y; acc.z += a.z; acc.w += a.w;
                }
            }
        }

        float d = dinv[nc];
        float4 v;
        v.x = fmaxf(fmaf(acc.x, d, bi.x), 0.0f);
        v.y = fmaxf(fmaf(acc.y, d, bi.y), 0.0f);
        v.z = fmaxf(fmaf(acc.z, d, bi.z), 0.0f);
        v.w = fmaxf(fmaf(acc.w, d, bi.w), 0.0f);

        // acc2[4l..4l+3] = sum_k v_k * W[k][c]; v_k at lane gbase+(k>>2), comp k&3
        float4 acc2 = make_float4(0.f, 0.f, 0.f, 0.f);
#pragma unroll
        for (int kk = 0; kk < 16; ++kk) {
            float v0 = __shfl(v.x, gbase + kk, 64);
            float v1 = __shfl(v.y, gbase + kk, 64);
            float v2 = __shfl(v.z, gbase + kk, 64);
            float v3 = __shfl(v.w, gbase + kk, 64);
            const float4 w0 = *(const float4*)&Ws[(4 * kk + 0) * CH + 4 * l];
            const float4 w1 = *(const float4*)&Ws[(4 * kk + 1) * CH + 4 * l];
            const float4 w2 = *(const float4*)&Ws[(4 * kk + 2) * CH + 4 * l];
            const float4 w3 = *(const float4*)&Ws[(4 * kk + 3) * CH + 4 * l];
            acc2.x = fmaf(v0, w0.x, acc2.x); acc2.y = fmaf(v0, w0.y, acc2.y);
            acc2.z = fmaf(v0, w0.z, acc2.z); acc2.w = fmaf(v0, w0.w, acc2.w);
            acc2.x = fmaf(v1, w1.x, acc2.x); acc2.y = fmaf(v1, w1.y, acc2.y);
            acc2.z = fmaf(v1, w1.z, acc2.z); acc2.w = fmaf(v1, w1.w, acc2.w);
            acc2.x = fmaf(v2, w2.x, acc2.x); acc2.y = fmaf(v2, w2.y, acc2.y);
            acc2.z = fmaf(v2, w2.z, acc2.z); acc2.w = fmaf(v2, w2.w, acc2.w);
            acc2.x = fmaf(v3, w3.x, acc2.x); acc2.y = fmaf(v3, w3.y, acc2.y);
            acc2.z = fmaf(v3, w3.z, acc2.z); acc2.w = fmaf(v3, w3.w, acc2.w);
        }

        // z[node] = d * (acc2 . Wl); reduce over the 16 lanes of the group
        float p = d * (acc2.x * wl4.x + acc2.y * wl4.y + acc2.z * wl4.z + acc2.w * wl4.w);
        p += __shfl_xor(p, 1, 64);
        p += __shfl_xor(p, 2, 64);
        p += __shfl_xor(p, 4, 64);
        p += __shfl_xor(p, 8, 64);
        if (node < n && l == 0) z[node] = p;
    }
}

// ---- head: out[n] = sigmoid(dinv[n]*(z[n]+sum z[s]) + (b2.Wl + bl)) -------

__global__ __launch_bounds__(256) void k_head(const int* __restrict__ row_ptr,
                                              const int* __restrict__ col,
                                              const float* __restrict__ z,
                                              const float* __restrict__ dinv,
                                              const float* __restrict__ b2,
                                              const float* __restrict__ Wl,
                                              const float* __restrict__ bl,
                                              float* __restrict__ out, int n) {
    int lane = threadIdx.x & 63;
    float c0 = b2[lane] * Wl[lane];
#pragma unroll
    for (int o = 32; o > 0; o >>= 1) c0 += __shfl_xor(c0, o, 64);
    c0 += bl[0];

    int tid = blockIdx.x * blockDim.x + threadIdx.x;
    int st  = gridDim.x * blockDim.x;
    for (int node = tid; node < n; node += st) {
        int beg = row_ptr[node];
        int end = row_ptr[node + 1];
        float s = z[node];
        int e = beg;
        for (; e + 4 <= end; e += 4) {
            float t0 = z[col[e]];
            float t1 = z[col[e + 1]];
            float t2 = z[col[e + 2]];
            float t3 = z[col[e + 3]];
            s += t0; s += t1; s += t2; s += t3;
        }
        for (; e < end; ++e) s += z[col[e]];
        float v = dinv[node] * s + c0;
        out[node] = 1.0f / (1.0f + expf(-v));
    }
}

// ---- launch ---------------------------------------------------------------

extern "C" void kernel_launch(void* const* d_in, const int* in_sizes, int n_in,
                              void* d_out, int out_size, void* d_ws, size_t ws_size,
                              hipStream_t stream) {
    const float* x   = (const float*)d_in[0];
    const int*   ei  = (const int*)d_in[1];   // [2, E] row-major
    const float* W1  = (const float*)d_in[2];
    const float* b1  = (const float*)d_in[3];
    const float* W2  = (const float*)d_in[4];
    const float* b2  = (const float*)d_in[5];
    const float* Wl  = (const float*)d_in[6];
    const float* bl  = (const float*)d_in[7];
    float*       out = (float*)d_out;

    const int N = in_sizes[0] / CH;
    const int E = in_sizes[1] / 2;
    const int* src = ei;
    const int* dst = ei + E;

    const size_t Npad = ((size_t)N + 511) & ~(size_t)511;
    const size_t Epad = ((size_t)E + 511) & ~(size_t)511;

    float* A       = (float*)d_ws;                    // N*CH  (hs1)
    float* z       = A + (size_t)N * CH;              // N
    float* dinv    = z + Npad;                        // N
    int*   row_ptr = (int*)(dinv + Npad);             // N+1
    int*   col     = row_ptr + Npad;                  // E
    unsigned int* ebuf = (unsigned int*)(col + Epad); // E
    int*   blkhist = (int*)(ebuf + Epad);             // NBLK_P*NBUCK
    int*   off_t   = blkhist + NBLK_P * NBUCK;        // NBUCK*NBLK_P (transposed)
    int*   bbase   = off_t + NBLK_P * NBUCK;          // NBUCK+1
    int*   tot     = bbase + NBUCK + 64;              // NBUCK

    const int TB = 256;
    const int GRID = 2048;
    const int NB_USED = (N + BMASK) >> BSHIFT;

    // CSR build — scatter-free, no single-block serial stages
    k_hist<<<NBLK_P, TB, 0, stream>>>(dst, blkhist, E);
    k_bucketscan<<<NBUCK * 64 / TB, TB, 0, stream>>>(blkhist, off_t, tot);
    k_scantot<<<1, NBUCK, 0, stream>>>(tot, bbase, row_ptr, N);
    k_partition<<<NBLK_P, TB, 0, stream>>>(src, dst, off_t, bbase, ebuf, E);
    k_bucket_csr<<<NB_USED, 128, 0, stream>>>(ebuf, bbase, row_ptr, dinv, col, N);

    // Layer 1: A = (x @ W1) * dinv
    k_gemm64<<<GRID, TB, 0, stream>>>(x, W1, dinv, A, N);

    // Layer 2 fused: gather(A) -> relu(agg1+b1) @ W2 * dinv -> dot(Wl) -> z
    k_gather_gemm<<<GRID, TB, 0, stream>>>(row_ptr, col, A, dinv, W2, b1, Wl, z, N);

    // Head: scalar gather over z + sigmoid
    k_head<<<(N + TB - 1) / TB, TB, 0, stream>>>(row_ptr, col, z, dinv, b2, Wl, bl, out, N);
}

// Round 7
// 364.637 us; speedup vs baseline: 1.3994x; 1.3994x over previous
//
#include <hip/hip_runtime.h>

#define CH 64
#define NBUCK 1024        // buckets = dst >> 7 (128 nodes/bucket); needs N <= 131072
#define BSHIFT 7
#define BMASK 127
#define NBLK_P 128        // partition blocks; must match k_hist/k_partition/k_bucketscan

// ---- CSR build: scatter-free two-level bucket sort ------------------------

__global__ __launch_bounds__(256) void k_hist(const int* __restrict__ dst,
                                              int* __restrict__ blkhist, int E) {
    __shared__ int h[NBUCK];
    for (int i = threadIdx.x; i < NBUCK; i += blockDim.x) h[i] = 0;
    __syncthreads();
    int chunk = (E + NBLK_P - 1) / NBLK_P;
    int beg = blockIdx.x * chunk;
    int end = min(beg + chunk, E);
    for (int e = beg + threadIdx.x; e < end; e += blockDim.x)
        atomicAdd(&h[dst[e] >> BSHIFT], 1);
    __syncthreads();
    for (int i = threadIdx.x; i < NBUCK; i += blockDim.x)
        blkhist[blockIdx.x * NBUCK + i] = h[i];
}

// One wave per bucket: scan blkhist[b][t] along b (128 values, 2/lane).
__global__ __launch_bounds__(256) void k_bucketscan(const int* __restrict__ blkhist,
                                                    int* __restrict__ off_t,
                                                    int* __restrict__ tot) {
    int lane = threadIdx.x & 63;
    int t = (blockIdx.x * blockDim.x + threadIdx.x) >> 6;   // bucket id 0..1023
    int b0 = lane * 2, b1 = b0 + 1;
    int v0 = blkhist[b0 * NBUCK + t];
    int v1 = blkhist[b1 * NBUCK + t];
    int ps = v0 + v1;
    int sc = ps;
#pragma unroll
    for (int o = 1; o < 64; o <<= 1) {
        int u = __shfl_up(sc, o, 64);
        if (lane >= o) sc += u;
    }
    int excl = sc - ps;
    off_t[t * NBLK_P + b0] = excl;
    off_t[t * NBLK_P + b1] = excl + v0;
    if (lane == 63) tot[t] = sc;
}

// Single small block: exclusive scan of 1024 bucket totals -> bbase.
__global__ __launch_bounds__(1024) void k_scantot(const int* __restrict__ tot,
                                                  int* __restrict__ bbase,
                                                  int* __restrict__ row_ptr, int n) {
    __shared__ int sh[NBUCK];
    int t = threadIdx.x;
    int v = tot[t];
    sh[t] = v;
    __syncthreads();
    for (int o = 1; o < NBUCK; o <<= 1) {
        int u = (t >= o) ? sh[t - o] : 0;
        __syncthreads();
        sh[t] += u;
        __syncthreads();
    }
    bbase[t] = sh[t] - v;
    if (t == NBUCK - 1) {
        bbase[NBUCK] = sh[t];
        row_ptr[n]   = sh[t];
    }
}

__global__ __launch_bounds__(256) void k_partition(const int* __restrict__ src,
                                                   const int* __restrict__ dst,
                                                   const int* __restrict__ off_t,
                                                   const int* __restrict__ bbase,
                                                   unsigned int* __restrict__ ebuf, int E) {
    __shared__ int cur[NBUCK];
    for (int i = threadIdx.x; i < NBUCK; i += blockDim.x)
        cur[i] = bbase[i] + off_t[i * NBLK_P + blockIdx.x];
    __syncthreads();
    int chunk = (E + NBLK_P - 1) / NBLK_P;
    int beg = blockIdx.x * chunk;
    int end = min(beg + chunk, E);
    for (int e = beg + threadIdx.x; e < end; e += blockDim.x) {
        int s = src[e];
        int d = dst[e];
        int p = atomicAdd(&cur[d >> BSHIFT], 1);
        ebuf[p] = ((unsigned int)(d & BMASK) << 17) | (unsigned int)s;
    }
}

__global__ __launch_bounds__(128) void k_bucket_csr(const unsigned int* __restrict__ ebuf,
                                                    const int* __restrict__ bbase,
                                                    int* __restrict__ row_ptr,
                                                    float* __restrict__ dinv,
                                                    int* __restrict__ col, int n) {
    __shared__ int cnt[128];
    __shared__ int cur[128];
    __shared__ int sc[128];
    int t = threadIdx.x;
    int k = blockIdx.x;
    int e0 = bbase[k], e1 = bbase[k + 1];
    cnt[t] = 0;
    __syncthreads();
    for (int e = e0 + t; e < e1; e += 128)
        atomicAdd(&cnt[ebuf[e] >> 17], 1);
    __syncthreads();
    int c = cnt[t];
    sc[t] = c;
    __syncthreads();
    for (int o = 1; o < 128; o <<= 1) {
        int v = (t >= o) ? sc[t - o] : 0;
        __syncthreads();
        sc[t] += v;
        __syncthreads();
    }
    int excl = sc[t] - c;
    int node = (k << BSHIFT) + t;
    if (node < n) {
        row_ptr[node] = e0 + excl;
        dinv[node] = rsqrtf((float)(c + 1));   // +1 self-loop
    }
    cur[t] = e0 + excl;
    __syncthreads();
    for (int e = e0 + t; e < e1; e += 128) {
        unsigned int u = ebuf[e];
        int p = atomicAdd(&cur[u >> 17], 1);
        col[p] = (int)(u & 0x1FFFFu);
    }
}

// ---- GEMM: wave-per-node, W in LDS, x-row broadcast via shuffle -----------

__global__ __launch_bounds__(256) void k_gemm64(const float* __restrict__ in,
                                                const float* __restrict__ W,
                                                const float* __restrict__ dinv,
                                                float* __restrict__ hs, int n) {
    __shared__ float Ws[CH * CH];
    for (int i = threadIdx.x; i < CH * CH; i += blockDim.x) Ws[i] = W[i];
    __syncthreads();

    int lane = threadIdx.x & 63;
    int wid  = (blockIdx.x * blockDim.x + threadIdx.x) >> 6;
    int nw   = (gridDim.x * blockDim.x) >> 6;

    for (int node = wid; node < n; node += nw) {
        float v = in[(size_t)node * CH + lane];
        float acc = 0.0f;
#pragma unroll
        for (int k = 0; k < CH; ++k)
            acc = fmaf(__shfl(v, k, 64), Ws[k * CH + lane], acc);
        hs[(size_t)node * CH + lane] = acc * dinv[node];
    }
}

// ---- fused: gather(agg1) + bias + relu + GEMM(W2) + dot(Wl) -> z ----------
// Round-4 shape (wave-per-node, 1 float/lane, wave-uniform scalar col loads,
// VGPR ~64 => 8 waves/SIMD) + 8-deep independent row-load unroll.

__global__ __launch_bounds__(256) void k_gather_gemm(const int* __restrict__ row_ptr,
                                                     const int* __restrict__ col,
                                                     const float* __restrict__ hs,
                                                     const float* __restrict__ dinv,
                                                     const float* __restrict__ W,
                                                     const float* __restrict__ bias,
                                                     const float* __restrict__ Wl,
                                                     float* __restrict__ z, int n) {
    __shared__ float Ws[CH * CH];
    for (int i = threadIdx.x; i < CH * CH; i += blockDim.x) Ws[i] = W[i];
    __syncthreads();

    int lane = threadIdx.x & 63;
    int wid  = (blockIdx.x * blockDim.x + threadIdx.x) >> 6;
    int nw   = (gridDim.x * blockDim.x) >> 6;
    float wl = Wl[lane];
    float bi = bias[lane];

    for (int node = wid; node < n; node += nw) {
        int beg = row_ptr[node];
        int end = row_ptr[node + 1];
        float acc = hs[(size_t)node * CH + lane];  // self-loop term

        int e = beg;
        for (; e + 8 <= end; e += 8) {             // 8 independent 256B row loads
            int s0 = col[e + 0], s1 = col[e + 1], s2 = col[e + 2], s3 = col[e + 3];
            int s4 = col[e + 4], s5 = col[e + 5], s6 = col[e + 6], s7 = col[e + 7];
            float a0 = hs[(size_t)s0 * CH + lane];
            float a1 = hs[(size_t)s1 * CH + lane];
            float a2 = hs[(size_t)s2 * CH + lane];
            float a3 = hs[(size_t)s3 * CH + lane];
            float a4 = hs[(size_t)s4 * CH + lane];
            float a5 = hs[(size_t)s5 * CH + lane];
            float a6 = hs[(size_t)s6 * CH + lane];
            float a7 = hs[(size_t)s7 * CH + lane];
            acc += a0; acc += a1; acc += a2; acc += a3;
            acc += a4; acc += a5; acc += a6; acc += a7;
        }
        for (; e < end; ++e)
            acc += hs[(size_t)col[e] * CH + lane];

        float d = dinv[node];
        float v = fmaxf(fmaf(acc, d, bi), 0.0f);   // h1 row = relu(agg1 + b1)
        float acc2 = 0.0f;
#pragma unroll
        for (int k = 0; k < CH; ++k)
            acc2 = fmaf(__shfl(v, k, 64), Ws[k * CH + lane], acc2);
        // z = (acc2 * d) . Wl   (wave reduction)
        float p = acc2 * d * wl;
#pragma unroll
        for (int o = 32; o > 0; o >>= 1) p += __shfl_xor(p, o, 64);
        if (lane == 0) z[node] = p;
    }
}

// ---- head: out[n] = sigmoid(dinv[n]*(z[n]+sum z[s]) + (b2.Wl + bl)) -------

__global__ __launch_bounds__(256) void k_head(const int* __restrict__ row_ptr,
                                              const int* __restrict__ col,
                                              const float* __restrict__ z,
                                              const float* __restrict__ dinv,
                                              const float* __restrict__ b2,
                                              const float* __restrict__ Wl,
                                              const float* __restrict__ bl,
                                              float* __restrict__ out, int n) {
    int lane = threadIdx.x & 63;
    float c0 = b2[lane] * Wl[lane];
#pragma unroll
    for (int o = 32; o > 0; o >>= 1) c0 += __shfl_xor(c0, o, 64);
    c0 += bl[0];

    int tid = blockIdx.x * blockDim.x + threadIdx.x;
    int st  = gridDim.x * blockDim.x;
    for (int node = tid; node < n; node += st) {
        int beg = row_ptr[node];
        int end = row_ptr[node + 1];
        float s = z[node];
        int e = beg;
        for (; e + 4 <= end; e += 4) {
            float t0 = z[col[e]];
            float t1 = z[col[e + 1]];
            float t2 = z[col[e + 2]];
            float t3 = z[col[e + 3]];
            s += t0; s += t1; s += t2; s += t3;
        }
        for (; e < end; ++e) s += z[col[e]];
        float v = dinv[node] * s + c0;
        out[node] = 1.0f / (1.0f + expf(-v));
    }
}

// ---- launch ---------------------------------------------------------------

extern "C" void kernel_launch(void* const* d_in, const int* in_sizes, int n_in,
                              void* d_out, int out_size, void* d_ws, size_t ws_size,
                              hipStream_t stream) {
    const float* x   = (const float*)d_in[0];
    const int*   ei  = (const int*)d_in[1];   // [2, E] row-major
    const float* W1  = (const float*)d_in[2];
    const float* b1  = (const float*)d_in[3];
    const float* W2  = (const float*)d_in[4];
    const float* b2  = (const float*)d_in[5];
    const float* Wl  = (const float*)d_in[6];
    const float* bl  = (const float*)d_in[7];
    float*       out = (float*)d_out;

    const int N = in_sizes[0] / CH;
    const int E = in_sizes[1] / 2;
    const int* src = ei;
    const int* dst = ei + E;

    const size_t Npad = ((size_t)N + 511) & ~(size_t)511;
    const size_t Epad = ((size_t)E + 511) & ~(size_t)511;

    float* A       = (float*)d_ws;                    // N*CH  (hs1)
    float* z       = A + (size_t)N * CH;              // N
    float* dinv    = z + Npad;                        // N
    int*   row_ptr = (int*)(dinv + Npad);             // N+1
    int*   col     = row_ptr + Npad;                  // E
    unsigned int* ebuf = (unsigned int*)(col + Epad); // E
    int*   blkhist = (int*)(ebuf + Epad);             // NBLK_P*NBUCK
    int*   off_t   = blkhist + NBLK_P * NBUCK;        // NBUCK*NBLK_P (transposed)
    int*   bbase   = off_t + NBLK_P * NBUCK;          // NBUCK+1
    int*   tot     = bbase + NBUCK + 64;              // NBUCK

    const int TB = 256;
    const int GRID = 2048;
    const int NB_USED = (N + BMASK) >> BSHIFT;

    // CSR build — scatter-free, no single-block serial stages
    k_hist<<<NBLK_P, TB, 0, stream>>>(dst, blkhist, E);
    k_bucketscan<<<NBUCK * 64 / TB, TB, 0, stream>>>(blkhist, off_t, tot);
    k_scantot<<<1, NBUCK, 0, stream>>>(tot, bbase, row_ptr, N);
    k_partition<<<NBLK_P, TB, 0, stream>>>(src, dst, off_t, bbase, ebuf, E);
    k_bucket_csr<<<NB_USED, 128, 0, stream>>>(ebuf, bbase, row_ptr, dinv, col, N);

    // Layer 1: A = (x @ W1) * dinv
    k_gemm64<<<GRID, TB, 0, stream>>>(x, W1, dinv, A, N);

    // Layer 2 fused: gather(A) -> relu(agg1+b1) @ W2 * dinv -> dot(Wl) -> z
    k_gather_gemm<<<GRID, TB, 0, stream>>>(row_ptr, col, A, dinv, W2, b1, Wl, z, N);

    // Head: scalar gather over z + sigmoid
    k_head<<<(N + TB - 1) / TB, TB, 0, stream>>>(row_ptr, col, z, dinv, b2, Wl, bl, out, N);
}